// Round 17
// baseline (79.297 us; speedup 1.0000x reference)
//
#include <hip/hip_runtime.h>

#define NTOT 4096
#define FD 32
#define BATCH 4
#define NBLK 256

typedef __attribute__((ext_vector_type(8))) _Float16 half8;
typedef __attribute__((ext_vector_type(4))) _Float16 half4;
typedef __attribute__((ext_vector_type(2))) _Float16 half2v;
typedef __attribute__((ext_vector_type(4))) float f32x4;

__device__ __forceinline__ float tanh_pos(float t) {
    float u = __builtin_amdgcn_exp2f(t * 2.885390081777927f); // e^{2t}
    float r = __builtin_amdgcn_rcpf(u + 1.0f);
    return __builtin_fmaf(-2.0f, r, 1.0f);
}

__device__ __forceinline__ float tanh_poly_f32(float t) {
    float t2 = t * t;
    float c = __builtin_fmaf(t2, 0.1333333333f, -0.3333333333f);
    return __builtin_fmaf(t * t2, c, t);
}

__device__ __forceinline__ float eluf(float x) {
    return x > 0.0f ? x : (__builtin_amdgcn_exp2f(x * 1.4426950408889634f) - 1.0f);
}

// Packed f16 relu + cubic tanh poly: p = max(h,0) * (1 - h^2/3)
__device__ __forceinline__ half4 pack_relu_poly(f32x4 s) {
    half2v a = __builtin_bit_cast(half2v, __builtin_amdgcn_cvt_pkrtz(s[0], s[1]));
    half2v b = __builtin_bit_cast(half2v, __builtin_amdgcn_cvt_pkrtz(s[2], s[3]));
    const half2v zero = {(_Float16)0.0f, (_Float16)0.0f};
    const half2v mth = {(_Float16)(-0.33333334f), (_Float16)(-0.33333334f)};
    const half2v one = {(_Float16)1.0f, (_Float16)1.0f};
    a = __builtin_elementwise_max(a, zero);
    b = __builtin_elementwise_max(b, zero);
    half2v a2 = a * a, b2 = b * b;
    half2v ca = a2 * mth + one, cb = b2 * mth + one;
    a = a * ca;
    b = b * cb;
    return __builtin_shufflevector(a, b, 0, 1, 2, 3);
}

// f32 slow path for the diagonal 16x16 tile: exact tanh(t+1) at c==r
__device__ __forceinline__ half4 diag_transform(f32x4 s, int l15, int lg) {
    float t[4];
#pragma unroll
    for (int e = 0; e < 4; ++e) t[e] = fmaxf(s[e], 0.0f);
#pragma unroll
    for (int e = 0; e < 4; ++e) {
        bool d = (lg * 4 + e == l15);
        t[e] = d ? tanh_pos(t[e] + 1.0f) : tanh_poly_f32(t[e]);
    }
    return __builtin_shufflevector(
        __builtin_bit_cast(half2v, __builtin_amdgcn_cvt_pkrtz(t[0], t[1])),
        __builtin_bit_cast(half2v, __builtin_amdgcn_cvt_pkrtz(t[2], t[3])), 0, 1, 2, 3);
}

// Device-wide barrier; all NBLK blocks are co-resident (1 block/CU).
__device__ __forceinline__ void grid_barrier(unsigned* ctr) {
    __syncthreads();
    if (threadIdx.x == 0) {
        __builtin_amdgcn_fence(__ATOMIC_RELEASE, "agent");
        __hip_atomic_fetch_add(ctr, 1u, __ATOMIC_RELAXED, __HIP_MEMORY_SCOPE_AGENT);
        while (__hip_atomic_load(ctr, __ATOMIC_RELAXED, __HIP_MEMORY_SCOPE_AGENT) < (unsigned)NBLK)
            __builtin_amdgcn_s_sleep(2);
        __builtin_amdgcn_fence(__ATOMIC_ACQUIRE, "agent");
    }
    __syncthreads();
}

// Fused: convert -> barrier -> layer0 -> barrier -> layer1.
// 256 blocks x 1024 threads (1 block/CU), each block owns 64 rows of one batch.
// Layer body is the R10 structure: 16 waves x 256-col strips, 8 unrolled iters.
__global__ __launch_bounds__(1024, 4) void fused_gcn(const float* __restrict__ X,
                                                     const float* __restrict__ Wg,
                                                     float* __restrict__ outF,
                                                     _Float16* __restrict__ Kf,
                                                     _Float16* __restrict__ Vf,
                                                     _Float16* __restrict__ H1,
                                                     unsigned* __restrict__ bar) {
    __shared__ char smem_raw[65536];  // convert staging / per-wave partials

    const int tid = threadIdx.x;
    const int lane = tid & 63;
    const int wv = tid >> 6;            // 16 waves
    const int blk = blockIdx.x;         // 256 blocks
    const int xcd = blk & 7;
    const int b = xcd >> 1;             // batch pinned to XCD pair
    const int rowidx = ((xcd & 1) << 5) | (blk >> 3);  // 0..63
    const int rowbase = rowidx << 6;                   // 64 rows per block
    const int l15 = lane & 15;
    const int lg = lane >> 4;

    _Float16* KfB = Kf + (size_t)b * NTOT * FD;
    _Float16* VfB = Vf + (size_t)b * NTOT * FD;
    _Float16* H1B = H1 + (size_t)b * NTOT * FD;

    // ================= Phase 0: convert own 64 rows =================
    {
        float* clds = (float*)smem_raw;  // [64][33] f32
        const float* Xp = X + ((size_t)b * NTOT + rowbase) * FD;
#pragma unroll
        for (int k = 0; k < 2; ++k) {
            int e = tid * 2 + k;
            clds[(e >> 5) * 33 + (e & 31)] = Xp[e];
        }
        __syncthreads();

        // Kfrag: 4 tiles x 64 lanes x 8; thread: tl=tid>>8, l=(tid>>2)&63, jj=tid&3 (2 f16)
        {
            const int tl = tid >> 8;
            const int l = (tid >> 2) & 63;
            const int jj = (tid & 3) * 2;
            const int row = tl * 16 + (l & 15);
            const int cb = (l >> 4) * 8 + jj;
            _Float16 h0 = (_Float16)clds[row * 33 + cb];
            _Float16 h1 = (_Float16)clds[row * 33 + cb + 1];
            half2v pk = {h0, h1};
            _Float16* dst = KfB + (size_t)((rowbase >> 4) + tl) * 512 + l * 8 + jj;
            *(unsigned*)dst = __builtin_bit_cast(unsigned, pk);
        }
        // Vfrag: 4 tiles x 2 fh x 64 lanes x 4; thread: tl=tid>>8, fh=(tid>>7)&1,
        // lv=(tid>>1)&63, jp=(tid&1)*2 (2 f16)
        {
            const int tl = tid >> 8;
            const int fh = (tid >> 7) & 1;
            const int lv = (tid >> 1) & 63;
            const int jp = (tid & 1) * 2;
            const int vl15 = lv & 15, vlg = lv >> 4;
            _Float16 h0 = (_Float16)clds[(tl * 16 + vlg * 4 + jp) * 33 + fh * 16 + vl15];
            _Float16 h1 = (_Float16)clds[(tl * 16 + vlg * 4 + jp + 1) * 33 + fh * 16 + vl15];
            half2v pk = {h0, h1};
            _Float16* dst = VfB + (size_t)(((rowbase >> 4) + tl) * 2 + fh) * 256 + lv * 4 + jp;
            *(unsigned*)dst = __builtin_bit_cast(unsigned, pk);
        }
    }
    grid_barrier(bar);

    // Q fragments: 4 row-tiles, shared by both layers (Q source is always X/Kfrag)
    half8 q[4];
#pragma unroll
    for (int qt = 0; qt < 4; ++qt)
        q[qt] = *(const half8*)(KfB + (size_t)((rowbase >> 4) + qt) * 512 + lane * 8);

    const int col0 = wv << 8;  // each wave owns 256 columns
    const int diagA = (rowbase - col0) >> 5;
    const f32x4 zero = {0.f, 0.f, 0.f, 0.f};
    _Float16* lds_part = (_Float16*)smem_raw;  // [16 wv][64 r][32 f] f16
    float* ldsf = (float*)smem_raw;            // f32 [r=64][f=32] after reduce

    // ================= Layers =================
#pragma unroll 1
    for (int layer = 0; layer < 2; ++layer) {
        const _Float16* Vsrc = (layer == 0) ? VfB : H1B;
        const float* W = Wg + layer * FD * FD;
        const _Float16* kq = KfB + (size_t)(col0 >> 4) * 512 + lane * 8;
        const _Float16* vq = Vsrc + (size_t)(col0 >> 4) * 512 + lane * 4;

        f32x4 accA[4], accB[4];
#pragma unroll
        for (int qt = 0; qt < 4; ++qt) {
            accA[qt] = zero;
            accB[qt] = zero;
        }

#pragma unroll
        for (int it = 0; it < 8; ++it) {
            const int base = it * 1024;
            half8 k0 = *(const half8*)(kq + base);
            half8 k1 = *(const half8*)(kq + base + 512);
            half4 v00 = *(const half4*)(vq + base);        // tile0, fh0
            half4 v01 = *(const half4*)(vq + base + 256);  // tile0, fh1
            half4 v10 = *(const half4*)(vq + base + 512);  // tile1, fh0
            half4 v11 = *(const half4*)(vq + base + 768);  // tile1, fh1

            f32x4 s0[4], s1[4];
#pragma unroll
            for (int qt = 0; qt < 4; ++qt) {
                s0[qt] = __builtin_amdgcn_mfma_f32_16x16x32_f16(k0, q[qt], zero, 0, 0, 0);
                s1[qt] = __builtin_amdgcn_mfma_f32_16x16x32_f16(k1, q[qt], zero, 0, 0, 0);
            }

            half4 p0[4], p1[4];
#pragma unroll
            for (int qt = 0; qt < 4; ++qt) {
                p0[qt] = pack_relu_poly(s0[qt]);
                p1[qt] = pack_relu_poly(s1[qt]);
            }
            if (it == diagA) {        // wave-uniform
                p0[0] = diag_transform(s0[0], l15, lg);
                p1[1] = diag_transform(s1[1], l15, lg);
            }
            if (it == diagA + 1) {    // wave-uniform
                p0[2] = diag_transform(s0[2], l15, lg);
                p1[3] = diag_transform(s1[3], l15, lg);
            }

#pragma unroll
            for (int qt = 0; qt < 4; ++qt) {
                accA[qt] = __builtin_amdgcn_mfma_f32_16x16x16f16(v00, p0[qt], accA[qt], 0, 0, 0);
                accB[qt] = __builtin_amdgcn_mfma_f32_16x16x16f16(v01, p0[qt], accB[qt], 0, 0, 0);
                accA[qt] = __builtin_amdgcn_mfma_f32_16x16x16f16(v10, p1[qt], accA[qt], 0, 0, 0);
                accB[qt] = __builtin_amdgcn_mfma_f32_16x16x16f16(v11, p1[qt], accB[qt], 0, 0, 0);
            }
        }

        // ---- store per-wave partial O^T as f16, layout [wv][r=64][f=32] ----
        __syncthreads();  // lds_part free (prev phase done)
#pragma unroll
        for (int qt = 0; qt < 4; ++qt) {
            half4 pa = __builtin_shufflevector(
                __builtin_bit_cast(half2v, __builtin_amdgcn_cvt_pkrtz(accA[qt][0], accA[qt][1])),
                __builtin_bit_cast(half2v, __builtin_amdgcn_cvt_pkrtz(accA[qt][2], accA[qt][3])), 0, 1, 2, 3);
            half4 pb = __builtin_shufflevector(
                __builtin_bit_cast(half2v, __builtin_amdgcn_cvt_pkrtz(accB[qt][0], accB[qt][1])),
                __builtin_bit_cast(half2v, __builtin_amdgcn_cvt_pkrtz(accB[qt][2], accB[qt][3])), 0, 1, 2, 3);
            int r = qt * 16 + l15;
            *(half4*)(lds_part + (wv * 64 + r) * 32 + lg * 4) = pa;
            *(half4*)(lds_part + (wv * 64 + r) * 32 + 16 + lg * 4) = pb;
        }
        __syncthreads();

        // ---- reduce 16 wave partials; thread owns slots tid, tid+1024 ----
        float red0 = 0.0f, red1 = 0.0f;
#pragma unroll
        for (int ww = 0; ww < 16; ++ww) {
            red0 += (float)lds_part[ww * 2048 + tid];
            red1 += (float)lds_part[ww * 2048 + tid + 1024];
        }
        __syncthreads();
        ldsf[tid] = red0;
        ldsf[tid + 1024] = red1;
        __syncthreads();

        // ---- G = O @ W, elu, write ----
        if (layer == 0) {
            const int jp = tid & 1;
            const int lane_v = (tid >> 1) & 63;
            const int fh = (tid >> 7) & 1;
            const int tl = tid >> 8;  // 0..3
            const int g = fh * 16 + (lane_v & 15);
            const int r0 = tl * 16 + ((lane_v >> 4) << 2) + jp * 2;
            float a0 = 0.0f, a1 = 0.0f;
#pragma unroll
            for (int f = 0; f < FD; ++f) {
                float w = W[f * FD + g];
                a0 = __builtin_fmaf(ldsf[r0 * FD + f], w, a0);
                a1 = __builtin_fmaf(ldsf[(r0 + 1) * FD + f], w, a1);
            }
            a0 = eluf(a0);
            a1 = eluf(a1);
            unsigned pk = __builtin_bit_cast(unsigned, __builtin_amdgcn_cvt_pkrtz(a0, a1));
            _Float16* dst = H1B +
                ((size_t)(((rowbase >> 4) + tl) * 2 + fh) * 64 + lane_v) * 4 + jp * 2;
            *(unsigned*)dst = pk;
            grid_barrier(bar + 16);  // H1 complete before layer 1
        } else {
            const int g = tid & 31, r0 = tid >> 5;  // rows r0, r0+32
            float a0 = 0.0f, a1 = 0.0f;
#pragma unroll
            for (int f = 0; f < FD; ++f) {
                float w = W[f * FD + g];
                a0 = __builtin_fmaf(ldsf[r0 * FD + f], w, a0);
                a1 = __builtin_fmaf(ldsf[(r0 + 32) * FD + f], w, a1);
            }
            a0 = eluf(a0);
            a1 = eluf(a1);
            float* dst = outF + ((size_t)b * NTOT + rowbase) * FD + g;
            dst[(size_t)r0 * FD] = a0;
            dst[(size_t)(r0 + 32) * FD] = a1;
        }
    }
}

extern "C" void kernel_launch(void* const* d_in, const int* in_sizes, int n_in,
                              void* d_out, int out_size, void* d_ws, size_t ws_size,
                              hipStream_t stream) {
    const float* X = (const float*)d_in[0];  // [B][NT][FD] f32
    const float* W = (const float*)d_in[1];  // [2][FD][FD] f32
    float* out = (float*)d_out;              // [B][NT][FD] f32

    _Float16* Kfrag = (_Float16*)d_ws;                    // 1 MB
    _Float16* VfragX = Kfrag + (size_t)BATCH * NTOT * FD; // 1 MB
    _Float16* H1frag = VfragX + (size_t)BATCH * NTOT * FD;// 1 MB
    unsigned* bar = (unsigned*)((char*)d_ws + 3u * 1024 * 1024);

    (void)hipMemsetAsync(bar, 0, 128, stream);  // zero both barrier counters
    fused_gcn<<<NBLK, 1024, 0, stream>>>(X, W, out, Kfrag, VfragX, H1frag, bar);
}

// Round 18
// 74.542 us; speedup vs baseline: 1.0638x; 1.0638x over previous
//
#include <hip/hip_runtime.h>

#define NTOT 4096
#define FD 32
#define BATCH 4
#define NBLK 256

typedef __attribute__((ext_vector_type(8))) _Float16 half8;
typedef __attribute__((ext_vector_type(4))) _Float16 half4;
typedef __attribute__((ext_vector_type(2))) _Float16 half2v;
typedef __attribute__((ext_vector_type(4))) float f32x4;

__device__ __forceinline__ float tanh_pos(float t) {
    float u = __builtin_amdgcn_exp2f(t * 2.885390081777927f); // e^{2t}
    float r = __builtin_amdgcn_rcpf(u + 1.0f);
    return __builtin_fmaf(-2.0f, r, 1.0f);
}

__device__ __forceinline__ float tanh_poly_f32(float t) {
    float t2 = t * t;
    float c = __builtin_fmaf(t2, 0.1333333333f, -0.3333333333f);
    return __builtin_fmaf(t * t2, c, t);
}

__device__ __forceinline__ float eluf(float x) {
    return x > 0.0f ? x : (__builtin_amdgcn_exp2f(x * 1.4426950408889634f) - 1.0f);
}

// Packed f16 relu + cubic tanh poly: p = max(h,0) * (1 - h^2/3)
__device__ __forceinline__ half4 pack_relu_poly(f32x4 s) {
    half2v a = __builtin_bit_cast(half2v, __builtin_amdgcn_cvt_pkrtz(s[0], s[1]));
    half2v b = __builtin_bit_cast(half2v, __builtin_amdgcn_cvt_pkrtz(s[2], s[3]));
    const half2v zero = {(_Float16)0.0f, (_Float16)0.0f};
    const half2v mth = {(_Float16)(-0.33333334f), (_Float16)(-0.33333334f)};
    const half2v one = {(_Float16)1.0f, (_Float16)1.0f};
    a = __builtin_elementwise_max(a, zero);
    b = __builtin_elementwise_max(b, zero);
    half2v a2 = a * a, b2 = b * b;
    half2v ca = a2 * mth + one, cb = b2 * mth + one;
    a = a * ca;
    b = b * cb;
    return __builtin_shufflevector(a, b, 0, 1, 2, 3);
}

// f32 slow path for the diagonal 16x16 tile: exact tanh(t+1) at c==r
__device__ __forceinline__ half4 diag_transform(f32x4 s, int l15, int lg) {
    float t[4];
#pragma unroll
    for (int e = 0; e < 4; ++e) t[e] = fmaxf(s[e], 0.0f);
#pragma unroll
    for (int e = 0; e < 4; ++e) {
        bool d = (lg * 4 + e == l15);
        t[e] = d ? tanh_pos(t[e] + 1.0f) : tanh_poly_f32(t[e]);
    }
    return __builtin_shufflevector(
        __builtin_bit_cast(half2v, __builtin_amdgcn_cvt_pkrtz(t[0], t[1])),
        __builtin_bit_cast(half2v, __builtin_amdgcn_cvt_pkrtz(t[2], t[3])), 0, 1, 2, 3);
}

// Device-wide barrier; all NBLK blocks are co-resident (1 block/CU).
__device__ __forceinline__ void grid_barrier(unsigned* ctr) {
    __syncthreads();
    if (threadIdx.x == 0) {
        __builtin_amdgcn_fence(__ATOMIC_RELEASE, "agent");
        __hip_atomic_fetch_add(ctr, 1u, __ATOMIC_RELAXED, __HIP_MEMORY_SCOPE_AGENT);
        while (__hip_atomic_load(ctr, __ATOMIC_RELAXED, __HIP_MEMORY_SCOPE_AGENT) < (unsigned)NBLK)
            __builtin_amdgcn_s_sleep(2);
        __builtin_amdgcn_fence(__ATOMIC_ACQUIRE, "agent");
    }
    __syncthreads();
}

// One layer, compile-time specialized (separate inlined copies -> full regalloc).
// R10 structure: 16 waves x 256-col strips, 8 fully unrolled iters of 32 cols.
template <int LAYER>
__device__ __forceinline__ void layer_body(const _Float16* __restrict__ KfB,
                                           const _Float16* __restrict__ Vsrc,
                                           const float* __restrict__ W,
                                           _Float16* __restrict__ H1B,
                                           float* __restrict__ outF,
                                           char* smem_raw, const half8* q,
                                           int tid, int lane, int wv, int b,
                                           int rowbase, int l15, int lg,
                                           int col0, int diagA) {
    const f32x4 zero = {0.f, 0.f, 0.f, 0.f};
    const _Float16* kq = KfB + (size_t)(col0 >> 4) * 512 + lane * 8;
    const _Float16* vq = Vsrc + (size_t)(col0 >> 4) * 512 + lane * 4;
    _Float16* lds_part = (_Float16*)smem_raw;  // [16 wv][64 r][32 f] f16
    float* ldsf = (float*)smem_raw;            // f32 [r=64][f=32] after reduce

    f32x4 accA[4], accB[4];
#pragma unroll
    for (int qt = 0; qt < 4; ++qt) {
        accA[qt] = zero;
        accB[qt] = zero;
    }

#pragma unroll
    for (int it = 0; it < 8; ++it) {
        const int base = it * 1024;
        half8 k0 = *(const half8*)(kq + base);
        half8 k1 = *(const half8*)(kq + base + 512);
        half4 v00 = *(const half4*)(vq + base);        // tile0, fh0
        half4 v01 = *(const half4*)(vq + base + 256);  // tile0, fh1
        half4 v10 = *(const half4*)(vq + base + 512);  // tile1, fh0
        half4 v11 = *(const half4*)(vq + base + 768);  // tile1, fh1

        f32x4 s0[4], s1[4];
#pragma unroll
        for (int qt = 0; qt < 4; ++qt) {
            s0[qt] = __builtin_amdgcn_mfma_f32_16x16x32_f16(k0, q[qt], zero, 0, 0, 0);
            s1[qt] = __builtin_amdgcn_mfma_f32_16x16x32_f16(k1, q[qt], zero, 0, 0, 0);
        }

        half4 p0[4], p1[4];
#pragma unroll
        for (int qt = 0; qt < 4; ++qt) {
            p0[qt] = pack_relu_poly(s0[qt]);
            p1[qt] = pack_relu_poly(s1[qt]);
        }
        if (it == diagA) {        // wave-uniform
            p0[0] = diag_transform(s0[0], l15, lg);
            p1[1] = diag_transform(s1[1], l15, lg);
        }
        if (it == diagA + 1) {    // wave-uniform
            p0[2] = diag_transform(s0[2], l15, lg);
            p1[3] = diag_transform(s1[3], l15, lg);
        }

#pragma unroll
        for (int qt = 0; qt < 4; ++qt) {
            accA[qt] = __builtin_amdgcn_mfma_f32_16x16x16f16(v00, p0[qt], accA[qt], 0, 0, 0);
            accB[qt] = __builtin_amdgcn_mfma_f32_16x16x16f16(v01, p0[qt], accB[qt], 0, 0, 0);
            accA[qt] = __builtin_amdgcn_mfma_f32_16x16x16f16(v10, p1[qt], accA[qt], 0, 0, 0);
            accB[qt] = __builtin_amdgcn_mfma_f32_16x16x16f16(v11, p1[qt], accB[qt], 0, 0, 0);
        }
    }

    // ---- store per-wave partial O^T as f16, layout [wv][r=64][f=32] ----
    __syncthreads();  // smem free (prev phase done)
#pragma unroll
    for (int qt = 0; qt < 4; ++qt) {
        half4 pa = __builtin_shufflevector(
            __builtin_bit_cast(half2v, __builtin_amdgcn_cvt_pkrtz(accA[qt][0], accA[qt][1])),
            __builtin_bit_cast(half2v, __builtin_amdgcn_cvt_pkrtz(accA[qt][2], accA[qt][3])), 0, 1, 2, 3);
        half4 pb = __builtin_shufflevector(
            __builtin_bit_cast(half2v, __builtin_amdgcn_cvt_pkrtz(accB[qt][0], accB[qt][1])),
            __builtin_bit_cast(half2v, __builtin_amdgcn_cvt_pkrtz(accB[qt][2], accB[qt][3])), 0, 1, 2, 3);
        int r = qt * 16 + l15;
        *(half4*)(lds_part + (wv * 64 + r) * 32 + lg * 4) = pa;
        *(half4*)(lds_part + (wv * 64 + r) * 32 + 16 + lg * 4) = pb;
    }
    __syncthreads();

    // ---- reduce 16 wave partials; thread owns slots tid, tid+1024 ----
    float red0 = 0.0f, red1 = 0.0f;
#pragma unroll
    for (int ww = 0; ww < 16; ++ww) {
        red0 += (float)lds_part[ww * 2048 + tid];
        red1 += (float)lds_part[ww * 2048 + tid + 1024];
    }
    __syncthreads();
    ldsf[tid] = red0;
    ldsf[tid + 1024] = red1;
    __syncthreads();

    // ---- G = O @ W, elu, write ----
    if (LAYER == 0) {
        const int jp = tid & 1;
        const int lane_v = (tid >> 1) & 63;
        const int fh = (tid >> 7) & 1;
        const int tl = tid >> 8;  // 0..3
        const int g = fh * 16 + (lane_v & 15);
        const int r0 = tl * 16 + ((lane_v >> 4) << 2) + jp * 2;
        float a0 = 0.0f, a1 = 0.0f;
#pragma unroll
        for (int f = 0; f < FD; ++f) {
            float w = W[f * FD + g];
            a0 = __builtin_fmaf(ldsf[r0 * FD + f], w, a0);
            a1 = __builtin_fmaf(ldsf[(r0 + 1) * FD + f], w, a1);
        }
        a0 = eluf(a0);
        a1 = eluf(a1);
        unsigned pk = __builtin_bit_cast(unsigned, __builtin_amdgcn_cvt_pkrtz(a0, a1));
        _Float16* dst = H1B +
            ((size_t)(((rowbase >> 4) + tl) * 2 + fh) * 64 + lane_v) * 4 + jp * 2;
        *(unsigned*)dst = pk;
    } else {
        const int g = tid & 31, r0 = tid >> 5;  // rows r0, r0+32
        float a0 = 0.0f, a1 = 0.0f;
#pragma unroll
        for (int f = 0; f < FD; ++f) {
            float w = W[f * FD + g];
            a0 = __builtin_fmaf(ldsf[r0 * FD + f], w, a0);
            a1 = __builtin_fmaf(ldsf[(r0 + 32) * FD + f], w, a1);
        }
        a0 = eluf(a0);
        a1 = eluf(a1);
        float* dst = outF + ((size_t)b * NTOT + rowbase) * FD + g;
        dst[(size_t)r0 * FD] = a0;
        dst[(size_t)(r0 + 32) * FD] = a1;
    }
}

// Fused: convert -> barrier -> layer0 -> barrier -> layer1.
// 256 blocks x 1024 threads (1 block/CU), each block owns 64 rows of one batch.
__global__ __launch_bounds__(1024, 4) void fused_gcn(const float* __restrict__ X,
                                                     const float* __restrict__ Wg,
                                                     float* __restrict__ outF,
                                                     _Float16* __restrict__ Kf,
                                                     _Float16* __restrict__ Vf,
                                                     _Float16* __restrict__ H1,
                                                     unsigned* __restrict__ bar) {
    __shared__ char smem_raw[65536];  // convert staging / per-wave partials

    const int tid = threadIdx.x;
    const int lane = tid & 63;
    const int wv = tid >> 6;            // 16 waves
    const int blk = blockIdx.x;         // 256 blocks
    const int xcd = blk & 7;
    const int b = xcd >> 1;             // batch pinned to XCD pair
    const int rowidx = ((xcd & 1) << 5) | (blk >> 3);  // 0..63
    const int rowbase = rowidx << 6;                   // 64 rows per block
    const int l15 = lane & 15;
    const int lg = lane >> 4;

    _Float16* KfB = Kf + (size_t)b * NTOT * FD;
    _Float16* VfB = Vf + (size_t)b * NTOT * FD;
    _Float16* H1B = H1 + (size_t)b * NTOT * FD;

    // ================= Phase 0: convert own 64 rows =================
    {
        float* clds = (float*)smem_raw;  // [64][33] f32
        const float* Xp = X + ((size_t)b * NTOT + rowbase) * FD;
#pragma unroll
        for (int k = 0; k < 2; ++k) {
            int e = tid * 2 + k;
            clds[(e >> 5) * 33 + (e & 31)] = Xp[e];
        }
        __syncthreads();

        // Kfrag: 4 tiles x 64 lanes x 8; thread: tl=tid>>8, l=(tid>>2)&63, jj=tid&3 (2 f16)
        {
            const int tl = tid >> 8;
            const int l = (tid >> 2) & 63;
            const int jj = (tid & 3) * 2;
            const int row = tl * 16 + (l & 15);
            const int cb = (l >> 4) * 8 + jj;
            _Float16 h0 = (_Float16)clds[row * 33 + cb];
            _Float16 h1 = (_Float16)clds[row * 33 + cb + 1];
            half2v pk = {h0, h1};
            _Float16* dst = KfB + (size_t)((rowbase >> 4) + tl) * 512 + l * 8 + jj;
            *(unsigned*)dst = __builtin_bit_cast(unsigned, pk);
        }
        // Vfrag: 4 tiles x 2 fh x 64 lanes x 4
        {
            const int tl = tid >> 8;
            const int fh = (tid >> 7) & 1;
            const int lv = (tid >> 1) & 63;
            const int jp = (tid & 1) * 2;
            const int vl15 = lv & 15, vlg = lv >> 4;
            _Float16 h0 = (_Float16)clds[(tl * 16 + vlg * 4 + jp) * 33 + fh * 16 + vl15];
            _Float16 h1 = (_Float16)clds[(tl * 16 + vlg * 4 + jp + 1) * 33 + fh * 16 + vl15];
            half2v pk = {h0, h1};
            _Float16* dst = VfB + (size_t)(((rowbase >> 4) + tl) * 2 + fh) * 256 + lv * 4 + jp;
            *(unsigned*)dst = __builtin_bit_cast(unsigned, pk);
        }
    }
    grid_barrier(bar);

    // Q fragments: 4 row-tiles, shared by both layers
    half8 q[4];
#pragma unroll
    for (int qt = 0; qt < 4; ++qt)
        q[qt] = *(const half8*)(KfB + (size_t)((rowbase >> 4) + qt) * 512 + lane * 8);

    const int col0 = wv << 8;  // each wave owns 256 columns
    const int diagA = (rowbase - col0) >> 5;

    layer_body<0>(KfB, VfB, Wg, H1B, outF, smem_raw, q,
                  tid, lane, wv, b, rowbase, l15, lg, col0, diagA);
    grid_barrier(bar + 16);  // H1 complete before layer 1
    layer_body<1>(KfB, H1B, Wg + FD * FD, H1B, outF, smem_raw, q,
                  tid, lane, wv, b, rowbase, l15, lg, col0, diagA);
}

extern "C" void kernel_launch(void* const* d_in, const int* in_sizes, int n_in,
                              void* d_out, int out_size, void* d_ws, size_t ws_size,
                              hipStream_t stream) {
    const float* X = (const float*)d_in[0];  // [B][NT][FD] f32
    const float* W = (const float*)d_in[1];  // [2][FD][FD] f32
    float* out = (float*)d_out;              // [B][NT][FD] f32

    _Float16* Kfrag = (_Float16*)d_ws;                    // 1 MB
    _Float16* VfragX = Kfrag + (size_t)BATCH * NTOT * FD; // 1 MB
    _Float16* H1frag = VfragX + (size_t)BATCH * NTOT * FD;// 1 MB
    unsigned* bar = (unsigned*)((char*)d_ws + 3u * 1024 * 1024);

    (void)hipMemsetAsync(bar, 0, 128, stream);  // zero both barrier counters
    fused_gcn<<<NBLK, 1024, 0, stream>>>(X, W, out, Kfrag, VfragX, H1frag, bar);
}